// Round 8
// baseline (51.021 us; speedup 1.0000x reference)
//
#include <hip/hip_runtime.h>

typedef float f4 __attribute__((ext_vector_type(4)));

// Problem constants: B=8, N=8192, K=16, C_in=C_out=64
#define BB 8
#define NN 8192
#define KK 16
#define CC 64
#define TPB 64                   // tokens per chunk/block in k_main
#define THREADS 256
#define NCHUNK 1024              // 8 batches * 128 chunks
#define NTOK (BB * NN)
#define BN_EPS 1e-5f

// K0: transpose W (16KB) into d_ws once per call: wt[c][o] = W[o][c].
__global__ __launch_bounds__(256) void k_wt(
    const float* __restrict__ W, float* __restrict__ wt)
{
    const int i = blockIdx.x * 256 + threadIdx.x;   // i = c*64+o
    wt[i] = W[(i & 63) * 64 + (i >> 6)];
}

// K1: KNN-gather-mean in x-space + projection + BN partials.
// LDS slimmed to 21.5KB (knn stage 4KB + agg 17.4KB) -> 7 blocks/CU = 28
// waves/CU (was 16): the gather is latency/outstanding-request bound, so
// occupancy is the lever. W^T is read from global (L1-resident, 16KB).
__global__ __launch_bounds__(THREADS, 7) void k_main(
    const float* __restrict__ x, const int* __restrict__ knn,
    const float* __restrict__ wt, float* __restrict__ out,
    float* __restrict__ partials)
{
    __shared__ int sKnn[TPB * KK];                        // 4KB
    __shared__ union { float agg[TPB][CC + 4]; float red[2][16][CC]; } u;

    const int tid   = threadIdx.x;
    const int batch = blockIdx.x & 7;
    const int nb    = (blockIdx.x >> 3) * TPB;

    // Stage this block's knn slice: 1024 ints, one coalesced int4 per thread.
    ((int4*)sKnn)[tid] =
        ((const int4*)&knn[(size_t)(batch * NN + nb) * KK])[tid];
    __syncthreads();

    // ---- Phase A: gather-mean. 16 lanes per token; lane l owns channels 4l..4l+3.
    const int g = tid >> 4, l = tid & 15;
    const f4* __restrict__ x4b = (const f4*)x + (size_t)batch * NN * (CC / 4);

    for (int it = 0; it < 4; ++it) {
        const int t = it * 16 + g;
        int idxs[16];
        #pragma unroll
        for (int q = 0; q < 4; ++q) {                     // broadcast ds_read_b128
            const int4 ii = ((const int4*)sKnn)[t * 4 + q];
            idxs[q * 4 + 0] = ii.x; idxs[q * 4 + 1] = ii.y;
            idxs[q * 4 + 2] = ii.z; idxs[q * 4 + 3] = ii.w;
        }
        f4 v[16];
        #pragma unroll
        for (int k = 0; k < KK; ++k)
            v[k] = x4b[(size_t)idxs[k] * (CC / 4) + l];
        #pragma unroll
        for (int s = 8; s; s >>= 1)
            #pragma unroll
            for (int k = 0; k < s; ++k) v[k] += v[k + s];
        *(f4*)&u.agg[t][l * 4] = v[0] * (1.0f / KK);
    }
    __syncthreads();

    // ---- Phase B: projection. Thread (tq,oq): tokens tq*4..+3, outputs oq*4..+3.
    const int tq = tid >> 4, oq = tid & 15;
    const f4* __restrict__ wt4 = (const f4*)wt;
    float acc[4][4] = {};
    #pragma unroll
    for (int c4 = 0; c4 < CC; c4 += 4) {
        float av[4][4], wv[4][4];
        #pragma unroll
        for (int t = 0; t < 4; ++t) {
            const f4 tmp = *(const f4*)&u.agg[tq * 4 + t][c4];
            av[t][0] = tmp.x; av[t][1] = tmp.y; av[t][2] = tmp.z; av[t][3] = tmp.w;
        }
        #pragma unroll
        for (int cc = 0; cc < 4; ++cc) {                  // L1-resident broadcast
            const f4 tmp = wt4[(c4 + cc) * 16 + oq];
            wv[cc][0] = tmp.x; wv[cc][1] = tmp.y; wv[cc][2] = tmp.z; wv[cc][3] = tmp.w;
        }
        #pragma unroll
        for (int t = 0; t < 4; ++t)
            #pragma unroll
            for (int cc = 0; cc < 4; ++cc)
                #pragma unroll
                for (int o = 0; o < 4; ++o)
                    acc[t][o] += av[t][cc] * wv[cc][o];
    }

    // ---- Write agg (into d_out) — non-temporal
    f4* __restrict__ out4 = (f4*)out;
    #pragma unroll
    for (int t = 0; t < 4; ++t) {
        f4 r; r.x = acc[t][0]; r.y = acc[t][1]; r.z = acc[t][2]; r.w = acc[t][3];
        __builtin_nontemporal_store(
            r, &out4[(size_t)(batch * NN + nb + tq * 4 + t) * (CC / 4) + oq]);
    }

    // ---- Per-chunk BN partials (coalesced: partials[chunk][128])
    __syncthreads();   // before overwriting u.agg with u.red
    float ps[4] = {}, pq[4] = {};
    #pragma unroll
    for (int t = 0; t < 4; ++t)
        #pragma unroll
        for (int o = 0; o < 4; ++o) {
            ps[o] += acc[t][o];
            pq[o] += acc[t][o] * acc[t][o];
        }
    #pragma unroll
    for (int o = 0; o < 4; ++o) {
        u.red[0][tq][oq * 4 + o] = ps[o];
        u.red[1][tq][oq * 4 + o] = pq[o];
    }
    __syncthreads();
    if (tid < 128) {                       // 0..63 = sum(c), 64..127 = sumsq(c)
        const int w = tid >> 6, c = tid & 63;
        float s = 0.f;
        #pragma unroll
        for (int i = 0; i < 16; ++i) s += u.red[w][i][c];
        partials[(size_t)blockIdx.x * 128 + tid] = s;
    }
}

// K2: finalize BN stats -> ss[0..63]=scale, ss[64..127]=shift
__global__ __launch_bounds__(THREADS) void k_stats(
    const float* __restrict__ partials, const float* __restrict__ gamma,
    const float* __restrict__ beta, float* __restrict__ ss)
{
    __shared__ float sFin[8];
    const int tid = threadIdx.x;
    const int j = blockIdx.x;            // channel 0..63
    float s1 = 0.f, s2 = 0.f;
    for (int i = tid; i < NCHUNK; i += THREADS) {
        s1 += partials[(size_t)i * 128 + j];
        s2 += partials[(size_t)i * 128 + 64 + j];
    }
    #pragma unroll
    for (int off = 32; off; off >>= 1) {
        s1 += __shfl_down(s1, off);
        s2 += __shfl_down(s2, off);
    }
    if ((tid & 63) == 0) { sFin[tid >> 6] = s1; sFin[4 + (tid >> 6)] = s2; }
    __syncthreads();
    if (tid == 0) {
        const float S1 = sFin[0] + sFin[1] + sFin[2] + sFin[3];
        const float S2 = sFin[4] + sFin[5] + sFin[6] + sFin[7];
        const float invn = 1.0f / (float)NTOK;
        const float mu  = S1 * invn;
        const float var = S2 * invn - mu * mu;
        const float sc  = gamma[j] * rsqrtf(var + BN_EPS);
        ss[j]      = sc;
        ss[CC + j] = beta[j] - mu * sc;
    }
}

// K3: in-place normalize d_out: out = agg*scale[c] + shift[c]
__global__ __launch_bounds__(256) void k_norm(
    float* __restrict__ out, const float* __restrict__ ss)
{
    const int idx = blockIdx.x * 256 + threadIdx.x;   // f4 index
    f4* out4 = (f4*)out;
    const f4 a  = out4[idx];
    const int c4 = idx & (CC / 4 - 1);
    const f4 sc = ((const f4*)ss)[c4];
    const f4 sh = ((const f4*)ss)[CC / 4 + c4];
    f4 r;
    r.x = fmaf(a.x, sc.x, sh.x);
    r.y = fmaf(a.y, sc.y, sh.y);
    r.z = fmaf(a.z, sc.z, sh.z);
    r.w = fmaf(a.w, sc.w, sh.w);
    __builtin_nontemporal_store(r, &out4[idx]);
}

extern "C" void kernel_launch(void* const* d_in, const int* in_sizes, int n_in,
                              void* d_out, int out_size, void* d_ws, size_t ws_size,
                              hipStream_t stream)
{
    const float* x     = (const float*)d_in[0];
    const int*   knn   = (const int*)d_in[1];
    const float* W     = (const float*)d_in[2];
    const float* gamma = (const float*)d_in[3];
    const float* beta  = (const float*)d_in[4];
    float* out = (float*)d_out;

    float* partials = (float*)d_ws;              // 1024*128 floats = 512KB
    float* ss       = partials + NCHUNK * 128;   // 128 floats
    float* wt       = ss + 128;                  // 64*64 floats = 16KB

    k_wt   <<<CC * CC / 256, 256, 0, stream>>>(W, wt);
    k_main <<<NCHUNK, THREADS, 0, stream>>>(x, knn, wt, out, partials);
    k_stats<<<64, THREADS, 0, stream>>>(partials, gamma, beta, ss);
    k_norm <<<(NTOK * CC) / 4 / 256, 256, 0, stream>>>(out, ss);
}